// Round 3
// baseline (15169.958 us; speedup 1.0000x reference)
//
#include <hip/hip_runtime.h>
#include <hip/hip_bf16.h>

typedef __hip_bfloat16 bf16;

#define NPART 30000
#define NEDGE 300000
#define HD 128
#define NLAYER 10
#define NFLOAT_ARRAYS 43

// ---------------- dtype detect + convert-to-fp32 ----------------
// bounds = [0,1,0,1]. bf16: u16 = [0x0000,0x3F80,0x0000,0x3F80] -> u16[1]==0x3F80.
// fp32:  u16 = [0,0, 0,0x3F80, 0,0, 0,0x3F80]                   -> u16[1]==0x0000.
__device__ __forceinline__ bool detect_bf16(const unsigned short* braw) {
    return braw[1] == 0x3F80u;
}

struct ConvArgs {
    const void* src[NFLOAT_ARRAYS];
    int n[NFLOAT_ARRAYS];
    int off[NFLOAT_ARRAYS];
};

__global__ __launch_bounds__(256)
void k_convert(ConvArgs a, float* __restrict__ dst, const unsigned short* __restrict__ braw)
{
    const bool isb = detect_bf16(braw);
    const int aid = blockIdx.y;
    const int n = a.n[aid];
    float* o = dst + a.off[aid];
    const int stride = gridDim.x * 256;
    int i = blockIdx.x * 256 + threadIdx.x;
    if (isb) {
        const unsigned short* s = (const unsigned short*)a.src[aid];
        for (; i < n; i += stride) {
            const unsigned int u = ((unsigned int)s[i]) << 16;
            o[i] = __uint_as_float(u);
        }
    } else {
        const float* s = (const float*)a.src[aid];
        for (; i < n; i += stride) o[i] = s[i];
    }
}

// ---------------- fp32 gemv: thread j = output feature j, 8 rows/block ----------------
template<int K, int S>
__device__ __forceinline__ void gemv(const float* __restrict__ in,
                                     const float* __restrict__ W,
                                     const float* __restrict__ B,
                                     float acc[8])
{
    const int j = threadIdx.x;
    const float bb = B[j];
#pragma unroll
    for (int m = 0; m < 8; m++) acc[m] = bb;

    constexpr int K4 = (K / 4) * 4;
    for (int k = 0; k < K4; k += 4) {
        const float w0 = W[(k + 0) * HD + j];
        const float w1 = W[(k + 1) * HD + j];
        const float w2 = W[(k + 2) * HD + j];
        const float w3 = W[(k + 3) * HD + j];
#pragma unroll
        for (int m = 0; m < 8; m++) {
            const float4 x = *(const float4*)(in + m * S + k);
            float a = acc[m];
            a = fmaf(x.x, w0, a);
            a = fmaf(x.y, w1, a);
            a = fmaf(x.z, w2, a);
            a = fmaf(x.w, w3, a);
            acc[m] = a;
        }
    }
#pragma unroll
    for (int k = K4; k < K; k++) {
        const float w = W[k * HD + j];
#pragma unroll
        for (int m = 0; m < 8; m++) acc[m] = fmaf(in[m * S + k], w, acc[m]);
    }
}

__device__ __forceinline__ void layernorm8(const float acc[8],
                                           const float* __restrict__ g,
                                           const float* __restrict__ be,
                                           float* __restrict__ red,  // LDS [32]
                                           float out[8])
{
    const int j = threadIdx.x;
    const int wv = j >> 6, ln = j & 63;
#pragma unroll
    for (int m = 0; m < 8; m++) {
        float s = acc[m], ss = acc[m] * acc[m];
#pragma unroll
        for (int off = 32; off >= 1; off >>= 1) {
            s  += __shfl_xor(s, off);
            ss += __shfl_xor(ss, off);
        }
        if (ln == 0) {
            red[(wv * 8 + m) * 2 + 0] = s;
            red[(wv * 8 + m) * 2 + 1] = ss;
        }
    }
    __syncthreads();
    const float gj = g[j], bej = be[j];
#pragma unroll
    for (int m = 0; m < 8; m++) {
        const float S_ = red[m * 2 + 0] + red[(8 + m) * 2 + 0];
        const float SS = red[m * 2 + 1] + red[(8 + m) * 2 + 1];
        const float mu = S_ * (1.0f / 128.0f);
        const float var = SS * (1.0f / 128.0f) - mu * mu;
        out[m] = (acc[m] - mu) * rsqrtf(var + 1e-5f) * gj + bej;
    }
}

template<int K, int S>
__device__ __forceinline__ void mlp_ln(const float* __restrict__ xs,
                                       float* __restrict__ h1, float* __restrict__ h2,
                                       float* __restrict__ red,
                                       const float* W1, const float* B1,
                                       const float* W2, const float* B2,
                                       const float* W3, const float* B3,
                                       const float* g,  const float* be,
                                       float out[8])
{
    const int j = threadIdx.x;
    float acc[8];
    gemv<K, S>(xs, W1, B1, acc);
#pragma unroll
    for (int m = 0; m < 8; m++) h1[m * HD + j] = fmaxf(acc[m], 0.0f);
    __syncthreads();
    gemv<HD, HD>(h1, W2, B2, acc);
#pragma unroll
    for (int m = 0; m < 8; m++) h2[m * HD + j] = fmaxf(acc[m], 0.0f);
    __syncthreads();
    gemv<HD, HD>(h2, W3, B3, acc);
    layernorm8(acc, g, be, red, out);
}

// ---------------- node encoder ----------------
__global__ __launch_bounds__(128)
void k_node_enc(const float* __restrict__ vel, const float* __restrict__ pos,
                const float* __restrict__ bounds, const int* __restrict__ ptype,
                const float* __restrict__ emb,
                const float* W1, const float* B1, const float* W2, const float* B2,
                const float* W3, const float* B3, const float* g, const float* be,
                float* __restrict__ nodes)
{
    __shared__ __align__(16) float xs[8 * 32];
    __shared__ __align__(16) float h1[8 * HD];
    __shared__ __align__(16) float h2[8 * HD];
    __shared__ __align__(16) float red[32];
    const int j = threadIdx.x;
    const int i0 = blockIdx.x * 8;

    for (int idx = j; idx < 240; idx += 128) {
        const int m = idx / 30, k = idx - m * 30;
        const int i = i0 + m;
        float v;
        if (k < 10) {
            v = vel[i * 10 + k];
        } else if (k < 14) {
            const int q = k - 10;
            float sub;
            if (q < 2) sub = pos[i * 2 + q] - bounds[q * 2 + 0];
            else       sub = bounds[(q - 2) * 2 + 1] - pos[i * 2 + (q - 2)];
            const float dv = sub / 0.05f;
            v = fminf(fmaxf(dv, -1.0f), 1.0f);
        } else {
            v = emb[ptype[i] * 16 + (k - 14)];
        }
        xs[m * 32 + k] = v;
    }
    __syncthreads();
    float out[8];
    mlp_ln<30, 32>(xs, h1, h2, red, W1, B1, W2, B2, W3, B3, g, be, out);
#pragma unroll
    for (int m = 0; m < 8; m++) nodes[(i0 + m) * HD + j] = out[m];
}

// ---------------- edge encoder ----------------
__global__ __launch_bounds__(128)
void k_edge_enc(const float* __restrict__ pos, const int* __restrict__ snd,
                const int* __restrict__ rcv,
                const float* W1, const float* B1, const float* W2, const float* B2,
                const float* W3, const float* B3, const float* g, const float* be,
                float* __restrict__ edges)
{
    __shared__ __align__(16) float xs[8 * 4];
    __shared__ __align__(16) float h1[8 * HD];
    __shared__ __align__(16) float h2[8 * HD];
    __shared__ __align__(16) float red[32];
    const int j = threadIdx.x;
    const int e0 = blockIdx.x * 8;
    if (j < 8) {
        const int e = e0 + j;
        const int s = snd[e], r = rcv[e];
        const float dx = (pos[s * 2 + 0] - pos[r * 2 + 0]) / 0.05f;
        const float dy = (pos[s * 2 + 1] - pos[r * 2 + 1]) / 0.05f;
        xs[j * 4 + 0] = dx;
        xs[j * 4 + 1] = dy;
        xs[j * 4 + 2] = sqrtf(dx * dx + dy * dy);
    }
    __syncthreads();
    float out[8];
    mlp_ln<3, 4>(xs, h1, h2, red, W1, B1, W2, B2, W3, B3, g, be, out);
#pragma unroll
    for (int m = 0; m < 8; m++) edges[(e0 + m) * HD + j] = out[m];
}

// ---------------- per-layer edge update (+ scatter into agg) ----------------
__global__ __launch_bounds__(128)
void k_edge_layer(const float* __restrict__ nodes, float* __restrict__ edges,
                  float* __restrict__ agg,
                  const int* __restrict__ snd, const int* __restrict__ rcv,
                  const float* W1, const float* B1, const float* W2, const float* B2,
                  const float* W3, const float* B3, const float* g, const float* be)
{
    __shared__ __align__(16) float xs[8 * 384];
    __shared__ __align__(16) float h1[8 * HD];
    __shared__ __align__(16) float h2[8 * HD];
    __shared__ __align__(16) float red[32];
    const int j = threadIdx.x;
    const int e0 = blockIdx.x * 8;
    int rr[8];
#pragma unroll
    for (int m = 0; m < 8; m++) {
        const int e = e0 + m;
        const int s = snd[e];
        const int r = rcv[e];
        rr[m] = r;
        xs[m * 384 + j]       = edges[e * HD + j];
        xs[m * 384 + 128 + j] = nodes[s * HD + j];
        xs[m * 384 + 256 + j] = nodes[r * HD + j];
    }
    __syncthreads();
    float out[8];
    mlp_ln<384, 384>(xs, h1, h2, red, W1, B1, W2, B2, W3, B3, g, be, out);
#pragma unroll
    for (int m = 0; m < 8; m++) {
        const float v = xs[m * 384 + j] + out[m];  // residual (xs row 0..127 = old edge)
        edges[(e0 + m) * HD + j] = v;
        atomicAdd(&agg[rr[m] * HD + j], v);
    }
}

// ---------------- per-layer node update ----------------
__global__ __launch_bounds__(128)
void k_node_layer(float* __restrict__ nodes, const float* __restrict__ agg,
                  const float* W1, const float* B1, const float* W2, const float* B2,
                  const float* W3, const float* B3, const float* g, const float* be)
{
    __shared__ __align__(16) float xs[8 * 256];
    __shared__ __align__(16) float h1[8 * HD];
    __shared__ __align__(16) float h2[8 * HD];
    __shared__ __align__(16) float red[32];
    const int j = threadIdx.x;
    const int i0 = blockIdx.x * 8;
#pragma unroll
    for (int m = 0; m < 8; m++) {
        const int i = i0 + m;
        xs[m * 256 + j]       = nodes[i * HD + j];
        xs[m * 256 + 128 + j] = agg[i * HD + j];
    }
    __syncthreads();
    float out[8];
    mlp_ln<256, 256>(xs, h1, h2, red, W1, B1, W2, B2, W3, B3, g, be, out);
#pragma unroll
    for (int m = 0; m < 8; m++) {
        nodes[(i0 + m) * HD + j] = xs[m * 256 + j] + out[m];
    }
}

// ---------------- decoder + Euler integration (dual output dtype) ----------------
__global__ __launch_bounds__(128)
void k_decoder(const float* __restrict__ nodes,
               const float* W1, const float* B1, const float* W2, const float* B2,
               const float* W3, const float* B3,
               const float* __restrict__ vel, const float* __restrict__ pos,
               const float* __restrict__ tgt, const int* __restrict__ nonk,
               const unsigned short* __restrict__ braw, void* __restrict__ d_out)
{
    __shared__ __align__(16) float xs[8 * HD];
    __shared__ __align__(16) float h1[8 * HD];
    __shared__ __align__(16) float h2[8 * HD];
    const int j = threadIdx.x;
    const int i0 = blockIdx.x * 8;
    float acc[8];
#pragma unroll
    for (int m = 0; m < 8; m++) xs[m * HD + j] = nodes[(i0 + m) * HD + j];
    __syncthreads();
    gemv<HD, HD>(xs, W1, B1, acc);
#pragma unroll
    for (int m = 0; m < 8; m++) h1[m * HD + j] = fmaxf(acc[m], 0.0f);
    __syncthreads();
    gemv<HD, HD>(h1, W2, B2, acc);
#pragma unroll
    for (int m = 0; m < 8; m++) h2[m * HD + j] = fmaxf(acc[m], 0.0f);
    __syncthreads();
    if (j < 16) {
        const int m = j >> 1, d = j & 1, i = i0 + m;
        float a = B3[d];
        for (int k = 0; k < HD; k++) a = fmaf(h2[m * HD + k], W3[k * 2 + d], a);
        float pp = pos[i * 2 + d] + vel[i * 10 + 8 + d] + a;
        if (nonk[i] == 0) pp = tgt[i * 2 + d];
        if (detect_bf16(braw)) {
            bf16* o = (bf16*)d_out;
            o[i * 2 + d] = __float2bfloat16(a);
            o[2 * NPART + i * 2 + d] = __float2bfloat16(pp);
        } else {
            float* o = (float*)d_out;
            o[i * 2 + d] = a;
            o[2 * NPART + i * 2 + d] = pp;
        }
    }
}

extern "C" void kernel_launch(void* const* d_in, const int* in_sizes, int n_in,
                              void* d_out, int out_size, void* d_ws, size_t ws_size,
                              hipStream_t stream)
{
    // int inputs read directly
    const int* ptype = (const int*)d_in[4];
    const int* nonk  = (const int*)d_in[5];
    const int* snd   = (const int*)d_in[6];
    const int* rcv   = (const int*)d_in[7];
    const unsigned short* braw = (const unsigned short*)d_in[2];  // dtype probe

    // float arrays: d_in indices 0,1,2,3,8,9..46
    int fmap[NFLOAT_ARRAYS];
    {
        int c = 0;
        fmap[c++] = 0; fmap[c++] = 1; fmap[c++] = 2; fmap[c++] = 3; fmap[c++] = 8;
        for (int i = 9; i <= 46; i++) fmap[c++] = i;
    }
    ConvArgs ca;
    const float* fp[47];  // canonical fp32 pointer per d_in index
    float* cw = (float*)d_ws;
    int off = 0;
    for (int i = 0; i < NFLOAT_ARRAYS; i++) {
        ca.src[i] = d_in[fmap[i]];
        ca.n[i]   = in_sizes[fmap[i]];
        ca.off[i] = off;
        fp[fmap[i]] = cw + off;
        off += in_sizes[fmap[i]];
    }
    // workspace layout after converted arrays
    float* nodes = cw + ((off + 3) & ~3);
    float* agg   = nodes + (size_t)NPART * HD;
    float* edges = agg   + (size_t)NPART * HD;

    k_convert<<<dim3(64, NFLOAT_ARRAYS), 256, 0, stream>>>(ca, cw, braw);

    k_node_enc<<<NPART / 8, 128, 0, stream>>>(fp[0], fp[1], fp[2], ptype, fp[8],
        fp[9], fp[10], fp[11], fp[12], fp[13], fp[14], fp[15], fp[16], nodes);
    k_edge_enc<<<NEDGE / 8, 128, 0, stream>>>(fp[1], snd, rcv,
        fp[17], fp[18], fp[19], fp[20], fp[21], fp[22], fp[23], fp[24], edges);

    for (int l = 0; l < NLAYER; l++) {
        hipMemsetAsync(agg, 0, (size_t)NPART * HD * sizeof(float), stream);
        k_edge_layer<<<NEDGE / 8, 128, 0, stream>>>(nodes, edges, agg, snd, rcv,
            fp[25] + (size_t)l * 384 * HD, fp[26] + (size_t)l * HD,
            fp[27] + (size_t)l * HD * HD,  fp[28] + (size_t)l * HD,
            fp[29] + (size_t)l * HD * HD,  fp[30] + (size_t)l * HD,
            fp[31] + (size_t)l * HD,       fp[32] + (size_t)l * HD);
        k_node_layer<<<NPART / 8, 128, 0, stream>>>(nodes, agg,
            fp[33] + (size_t)l * 256 * HD, fp[34] + (size_t)l * HD,
            fp[35] + (size_t)l * HD * HD,  fp[36] + (size_t)l * HD,
            fp[37] + (size_t)l * HD * HD,  fp[38] + (size_t)l * HD,
            fp[39] + (size_t)l * HD,       fp[40] + (size_t)l * HD);
    }

    k_decoder<<<NPART / 8, 128, 0, stream>>>(nodes,
        fp[41], fp[42], fp[43], fp[44], fp[45], fp[46],
        fp[0], fp[1], fp[3], nonk, braw, d_out);
}